// Round 4
// baseline (162.454 us; speedup 1.0000x reference)
//
#include <hip/hip_runtime.h>
#include <hip/hip_bf16.h>

#define BATCH 8
#define CIN   64
#define COUT  64
#define HH    128
#define WW    128
#define HW    (HH * WW)
#define ALPHA 8.3f
#define TPX   64
#define YPB   2
#define XW    66

typedef __attribute__((ext_vector_type(8))) short short8;   // 8 bf16 = 4 VGPR
typedef __attribute__((ext_vector_type(4))) float f32x4;

// index (in shorts) into s_img[4][XW][64], XOR-swizzled in 8-short (16B) slots
__device__ __forceinline__ int img_idx(int r, int x, int c) {
    return (((r * XW + x) << 6) + c) ^ ((x & 7) << 3);
}

__global__ __launch_bounds__(256, 4)
void depthconv_fused(const float* __restrict__ image,
                     const float* __restrict__ depth,
                     const float* __restrict__ weight,   // [o][c][k] f32
                     const float* __restrict__ bias,
                     float* __restrict__ out) {
    __shared__ short s_img[4 * XW * 64];      // 33792 B, rows y0-1..y0+2
    __shared__ float s_d[4][XW];              //  1056 B
    __shared__ float s_sim[YPB][9][TPX];      //  4608 B

    const int tid = threadIdx.x;
    const int bid = blockIdx.x;
    const int yg = bid & 63;                  // 64 y-pairs
    const int xt = (bid >> 6) & 1;
    const int b  = bid >> 7;
    const int x0 = xt * TPX;
    const int y0 = yg * YPB;

    const int lane = tid & 63;
    const int wid  = tid >> 6;                // 4 waves, 16 couts each
    const int l15  = lane & 15;
    const int lq   = lane >> 4;
    const int o_base = wid * 16;

    // ---- A-fragments straight from [o][c][tap]: 72 contiguous floats per half ----
    // lane holds A[row=o][k=c]: o = o_base+l15, c = h*32 + lq*8 + j
    short8 wfrag[9][2];
    {
        const int o = o_base + l15;
        #pragma unroll
        for (int h = 0; h < 2; ++h) {
            const float* wp = &weight[(o * CIN + h * 32 + lq * 8) * 9];  // 16B-aligned
            #pragma unroll
            for (int q4 = 0; q4 < 18; ++q4) {
                float4 f = *(const float4*)&wp[q4 * 4];
                #pragma unroll
                for (int e = 0; e < 4; ++e) {
                    const int q  = q4 * 4 + e;        // q = cj*9 + tap (constant-folded)
                    const int cj = q / 9, tap = q % 9;
                    const float fe = (e == 0) ? f.x : (e == 1) ? f.y : (e == 2) ? f.z : f.w;
                    wfrag[tap][h][cj] =
                        __builtin_bit_cast(short, __float2bfloat16(fe));
                }
            }
        }
    }

    float bias_v[4];
    #pragma unroll
    for (int r = 0; r < 4; ++r) bias_v[r] = bias[o_base + lq * 4 + r];

    // ---- stage interior x=1..64: fixed (x,row) per thread, loop channels ----
    {
        const int sx  = 1 + (tid & 63);
        const int srr = tid >> 6;                       // 0..3
        const int gy  = y0 - 1 + srr;
        const int gx  = x0 + (tid & 63);                // always in [0,127]
        const bool yok = (unsigned)gy < HH;
        const float* ip = &image[((b * CIN) * HH + gy) * WW + gx];
        const int base = (srr * XW + sx) << 6;          // low 6 bits = 0
        const int swz  = (sx & 7) << 3;
        #pragma unroll 8
        for (int c2 = 0; c2 < 32; ++c2) {
            float v0 = 0.f, v1 = 0.f;
            if (yok) { v0 = ip[0]; v1 = ip[HW]; }
            ip += 2 * HW;
            __hip_bfloat162 pk = __float22bfloat162_rn(float2{v0, v1});
            *(__hip_bfloat162*)&s_img[base + ((2 * c2) ^ swz)] = pk;
        }
    }
    // ---- stage edge columns x=0,65: exactly one element-pair per thread ----
    {
        const int e   = tid & 1;
        const int sx  = e ? (XW - 1) : 0;
        const int rr  = (tid >> 1) & 3;
        const int c2  = tid >> 3;                       // 0..31
        const int gy  = y0 - 1 + rr;
        const int gx  = x0 - 1 + sx;
        float v0 = 0.f, v1 = 0.f;
        if ((unsigned)gy < HH && (unsigned)gx < WW) {
            const float* p = &image[((b * CIN + 2 * c2) * HH + gy) * WW + gx];
            v0 = p[0]; v1 = p[HW];
        }
        __hip_bfloat162 pk = __float22bfloat162_rn(float2{v0, v1});
        *(__hip_bfloat162*)&s_img[img_idx(rr, sx, 2 * c2)] = pk;
    }
    // ---- stage depth rows ----
    for (int i = tid; i < 4 * XW; i += 256) {
        int rr = i / XW, x = i - rr * XW;
        int gy = y0 - 1 + rr, gx = x0 - 1 + x;
        float v = 0.f;
        if ((unsigned)gy < HH && (unsigned)gx < WW)
            v = depth[(b * HH + gy) * WW + gx];
        s_d[rr][x] = v;
    }
    __syncthreads();

    // ---- sim[yy][tap][p] = exp(-a*|d - d_tap0|), tap0 = (-1,-1) ----
    for (int i = tid; i < YPB * 9 * TPX; i += 256) {
        int p  = i & 63;
        int t  = i >> 6;                                // 0..17
        int yy = t / 9, tap = t - yy * 9;
        int ri = tap / 3, dj = tap - ri * 3;
        float dt = s_d[yy + ri][p + dj];
        float dc = s_d[yy][p];
        s_sim[yy][tap][p] = __expf(-ALPHA * fabsf(dt - dc));
    }
    __syncthreads();

    // ---- per-y-row: 9 per-tap GEMMs + sim-weighted accumulate ----
    for (int yy = 0; yy < YPB; ++yy) {
        f32x4 acc[4];
        #pragma unroll
        for (int nt = 0; nt < 4; ++nt) acc[nt] = f32x4{0.f, 0.f, 0.f, 0.f};

        #pragma unroll
        for (int tap = 0; tap < 9; ++tap) {
            const int ri = tap / 3, dj = tap % 3;
            #pragma unroll
            for (int nt = 0; nt < 4; ++nt) {
                const int xi = nt * 16 + l15 + dj;
                short8 b0 = *(const short8*)&s_img[img_idx(yy + ri, xi, lq * 8)];
                f32x4 tmp = __builtin_amdgcn_mfma_f32_16x16x32_bf16(
                    wfrag[tap][0], b0, (f32x4){0.f, 0.f, 0.f, 0.f}, 0, 0, 0);
                short8 b1 = *(const short8*)&s_img[img_idx(yy + ri, xi, 32 + lq * 8)];
                tmp = __builtin_amdgcn_mfma_f32_16x16x32_bf16(
                    wfrag[tap][1], b1, tmp, 0, 0, 0);
                const float sv = s_sim[yy][tap][nt * 16 + l15];
                #pragma unroll
                for (int r = 0; r < 4; ++r)
                    acc[nt][r] = fmaf(sv, tmp[r], acc[nt][r]);
            }
        }

        const int y = y0 + yy;
        #pragma unroll
        for (int nt = 0; nt < 4; ++nt) {
            const int px = x0 + nt * 16 + l15;
            #pragma unroll
            for (int r = 0; r < 4; ++r) {
                const int o = o_base + lq * 4 + r;
                out[((b * COUT + o) * HH + y) * WW + px] = acc[nt][r] + bias_v[r];
            }
        }
    }
}

extern "C" void kernel_launch(void* const* d_in, const int* in_sizes, int n_in,
                              void* d_out, int out_size, void* d_ws, size_t ws_size,
                              hipStream_t stream) {
    const float* image  = (const float*)d_in[0];
    const float* depth  = (const float*)d_in[1];
    const float* weight = (const float*)d_in[2];
    const float* bias   = (const float*)d_in[3];
    float* out = (float*)d_out;

    dim3 grid(BATCH * (HH / YPB) * (WW / TPX));        // 8 * 64 * 2 = 1024
    depthconv_fused<<<grid, 256, 0, stream>>>(image, depth, weight, bias, out);
}

// Round 5
// 130.853 us; speedup vs baseline: 1.2415x; 1.2415x over previous
//
#include <hip/hip_runtime.h>
#include <hip/hip_bf16.h>

#define BATCH 8
#define CIN   64
#define COUT  64
#define HH    128
#define WW    128
#define HW    (HH * WW)
#define ALPHA 8.3f
#define TPX   64
#define YPB   2
#define XW    66

typedef __attribute__((ext_vector_type(8))) short short8;   // 8 bf16 = 4 VGPR
typedef __attribute__((ext_vector_type(4))) float f32x4;

// index (in shorts) into s_img[4][XW][64], XOR-swizzled in 8-short (16B) slots
__device__ __forceinline__ int img_idx(int r, int x, int c) {
    return (((r * XW + x) << 6) + c) ^ ((x & 7) << 3);
}

// NOTE: plain __launch_bounds__(256). Round 4's (256,4) min-occupancy bound
// capped VGPR at 64 < ~120 live -> wfrag spilled to scratch -> 200 MB of
// HBM spill traffic, kernel became scratch-BW-bound (95 us). Do not cap.
__global__ __launch_bounds__(256)
void depthconv_fused(const float* __restrict__ image,
                     const float* __restrict__ depth,
                     const float* __restrict__ weight,   // [o][c][k] f32
                     const float* __restrict__ bias,
                     float* __restrict__ out) {
    __shared__ short s_img[4 * XW * 64];      // 33792 B, rows y0-1..y0+2
    __shared__ float s_d[4][XW];              //  1056 B
    __shared__ float s_sim[YPB][9][TPX];      //  4608 B

    const int tid = threadIdx.x;
    const int bid = blockIdx.x;
    const int yg = bid & 63;                  // 64 y-pairs
    const int xt = (bid >> 6) & 1;
    const int b  = bid >> 7;
    const int x0 = xt * TPX;
    const int y0 = yg * YPB;

    const int lane = tid & 63;
    const int wid  = tid >> 6;                // 4 waves, 16 couts each
    const int l15  = lane & 15;
    const int lq   = lane >> 4;
    const int o_base = wid * 16;

    // ---- A-fragments straight from [o][c][tap]: 72 contiguous floats per half ----
    // lane holds A[row=o][k=c]: o = o_base+l15, c = h*32 + lq*8 + j
    short8 wfrag[9][2];
    {
        const int o = o_base + l15;
        #pragma unroll
        for (int h = 0; h < 2; ++h) {
            const float* wp = &weight[(o * CIN + h * 32 + lq * 8) * 9];  // 16B-aligned
            #pragma unroll
            for (int q4 = 0; q4 < 18; ++q4) {
                float4 f = *(const float4*)&wp[q4 * 4];
                #pragma unroll
                for (int e = 0; e < 4; ++e) {
                    const int q  = q4 * 4 + e;        // q = cj*9 + tap (constant-folded)
                    const int cj = q / 9, tap = q % 9;
                    const float fe = (e == 0) ? f.x : (e == 1) ? f.y : (e == 2) ? f.z : f.w;
                    wfrag[tap][h][cj] =
                        __builtin_bit_cast(short, __float2bfloat16(fe));
                }
            }
        }
    }

    float bias_v[4];
    #pragma unroll
    for (int r = 0; r < 4; ++r) bias_v[r] = bias[o_base + lq * 4 + r];

    // ---- stage interior x=1..64: fixed (x,row) per thread, loop channels ----
    {
        const int sx  = 1 + (tid & 63);
        const int srr = tid >> 6;                       // 0..3
        const int gy  = y0 - 1 + srr;
        const int gx  = x0 + (tid & 63);                // always in [0,127]
        const bool yok = (unsigned)gy < HH;
        const float* ip = &image[((b * CIN) * HH + gy) * WW + gx];
        const int base = (srr * XW + sx) << 6;          // low 6 bits = 0
        const int swz  = (sx & 7) << 3;
        #pragma unroll 8
        for (int c2 = 0; c2 < 32; ++c2) {
            float v0 = 0.f, v1 = 0.f;
            if (yok) { v0 = ip[0]; v1 = ip[HW]; }
            ip += 2 * HW;
            __hip_bfloat162 pk = __float22bfloat162_rn(float2{v0, v1});
            *(__hip_bfloat162*)&s_img[base + ((2 * c2) ^ swz)] = pk;
        }
    }
    // ---- stage edge columns x=0,65: exactly one element-pair per thread ----
    {
        const int e   = tid & 1;
        const int sx  = e ? (XW - 1) : 0;
        const int rr  = (tid >> 1) & 3;
        const int c2  = tid >> 3;                       // 0..31
        const int gy  = y0 - 1 + rr;
        const int gx  = x0 - 1 + sx;
        float v0 = 0.f, v1 = 0.f;
        if ((unsigned)gy < HH && (unsigned)gx < WW) {
            const float* p = &image[((b * CIN + 2 * c2) * HH + gy) * WW + gx];
            v0 = p[0]; v1 = p[HW];
        }
        __hip_bfloat162 pk = __float22bfloat162_rn(float2{v0, v1});
        *(__hip_bfloat162*)&s_img[img_idx(rr, sx, 2 * c2)] = pk;
    }
    // ---- stage depth rows ----
    for (int i = tid; i < 4 * XW; i += 256) {
        int rr = i / XW, x = i - rr * XW;
        int gy = y0 - 1 + rr, gx = x0 - 1 + x;
        float v = 0.f;
        if ((unsigned)gy < HH && (unsigned)gx < WW)
            v = depth[(b * HH + gy) * WW + gx];
        s_d[rr][x] = v;
    }
    __syncthreads();

    // ---- sim[yy][tap][p] = exp(-a*|d - d_tap0|), tap0 = (-1,-1) ----
    for (int i = tid; i < YPB * 9 * TPX; i += 256) {
        int p  = i & 63;
        int t  = i >> 6;                                // 0..17
        int yy = t / 9, tap = t - yy * 9;
        int ri = tap / 3, dj = tap - ri * 3;
        float dt = s_d[yy + ri][p + dj];
        float dc = s_d[yy][p];
        s_sim[yy][tap][p] = __expf(-ALPHA * fabsf(dt - dc));
    }
    __syncthreads();

    // ---- per-y-row: 9 per-tap GEMMs + sim-weighted accumulate ----
    for (int yy = 0; yy < YPB; ++yy) {
        f32x4 acc[4];
        #pragma unroll
        for (int nt = 0; nt < 4; ++nt) acc[nt] = f32x4{0.f, 0.f, 0.f, 0.f};

        #pragma unroll
        for (int tap = 0; tap < 9; ++tap) {
            const int ri = tap / 3, dj = tap % 3;
            #pragma unroll
            for (int nt = 0; nt < 4; ++nt) {
                const int xi = nt * 16 + l15 + dj;
                short8 b0 = *(const short8*)&s_img[img_idx(yy + ri, xi, lq * 8)];
                f32x4 tmp = __builtin_amdgcn_mfma_f32_16x16x32_bf16(
                    wfrag[tap][0], b0, (f32x4){0.f, 0.f, 0.f, 0.f}, 0, 0, 0);
                short8 b1 = *(const short8*)&s_img[img_idx(yy + ri, xi, 32 + lq * 8)];
                tmp = __builtin_amdgcn_mfma_f32_16x16x32_bf16(
                    wfrag[tap][1], b1, tmp, 0, 0, 0);
                const float sv = s_sim[yy][tap][nt * 16 + l15];
                #pragma unroll
                for (int r = 0; r < 4; ++r)
                    acc[nt][r] = fmaf(sv, tmp[r], acc[nt][r]);
            }
        }

        const int y = y0 + yy;
        #pragma unroll
        for (int nt = 0; nt < 4; ++nt) {
            const int px = x0 + nt * 16 + l15;
            #pragma unroll
            for (int r = 0; r < 4; ++r) {
                const int o = o_base + lq * 4 + r;
                out[((b * COUT + o) * HH + y) * WW + px] = acc[nt][r] + bias_v[r];
            }
        }
    }
}

extern "C" void kernel_launch(void* const* d_in, const int* in_sizes, int n_in,
                              void* d_out, int out_size, void* d_ws, size_t ws_size,
                              hipStream_t stream) {
    const float* image  = (const float*)d_in[0];
    const float* depth  = (const float*)d_in[1];
    const float* weight = (const float*)d_in[2];
    const float* bias   = (const float*)d_in[3];
    float* out = (float*)d_out;

    dim3 grid(BATCH * (HH / YPB) * (WW / TPX));        // 8 * 64 * 2 = 1024
    depthconv_fused<<<grid, 256, 0, stream>>>(image, depth, weight, bias, out);
}

// Round 6
// 121.487 us; speedup vs baseline: 1.3372x; 1.0771x over previous
//
#include <hip/hip_runtime.h>
#include <hip/hip_bf16.h>

#define BATCH 8
#define CIN   64
#define COUT  64
#define HH    128
#define WW    128
#define HW    (HH * WW)
#define ALPHA 8.3f
#define TPX   64
#define YPB   2
#define XW    66

typedef __attribute__((ext_vector_type(8))) short short8;   // 8 bf16 = 4 VGPR
typedef __attribute__((ext_vector_type(4))) float f32x4;

// index (in shorts) into s_img[4][XW][64], XOR-swizzled in 8-short (16B) slots
__device__ __forceinline__ int img_idx(int r, int x, int c) {
    return (((r * XW + x) << 6) + c) ^ ((x & 7) << 3);
}

// pre-kernel: weight [o][c][k] f32 -> wt [k][o][c] bf16 (cheap per-block frag loads)
__global__ __launch_bounds__(256)
void transpose_w(const float* __restrict__ w, __hip_bfloat16* __restrict__ wt) {
    int i = blockIdx.x * 256 + threadIdx.x;
    if (i >= 9 * 64 * 64) return;
    int c = i & 63;
    int o = (i >> 6) & 63;
    int tap = i >> 12;
    wt[i] = __float2bfloat16(w[(o * 64 + c) * 9 + tap]);
}

// NOTE: plain __launch_bounds__(256). (256,4) in Round 4 capped VGPR at 64 ->
// wfrag spilled -> 200 MB scratch HBM traffic. Do not cap.
__global__ __launch_bounds__(256)
void depthconv_fused(const float* __restrict__ image,
                     const float* __restrict__ depth,
                     const float* __restrict__ bias,
                     const short* __restrict__ wt,     // [9][64 o][64 c] bf16
                     float* __restrict__ out) {
    __shared__ short s_img[4 * XW * 64];      // 33792 B, rows y0-1..y0+2
    __shared__ float s_d[4][XW];              //  1056 B
    __shared__ float s_sim[YPB][9][TPX];      //  4608 B

    const int tid = threadIdx.x;
    const int bid = blockIdx.x;
    const int yg = bid & 63;                  // 64 y-pairs
    const int xt = (bid >> 6) & 1;
    const int b  = bid >> 7;
    const int x0 = xt * TPX;
    const int y0 = yg * YPB;

    const int lane = tid & 63;
    const int wid  = tid >> 6;                // 4 waves, 16 couts each
    const int l15  = lane & 15;
    const int lq   = lane >> 4;
    const int o_base = wid * 16;

    // ---- A-fragments from pre-transposed wt: 18 b128 loads, L2-resident ----
    short8 wfrag[9][2];
    #pragma unroll
    for (int tap = 0; tap < 9; ++tap)
        #pragma unroll
        for (int h = 0; h < 2; ++h)
            wfrag[tap][h] = *(const short8*)&wt[(tap * 64 + o_base + l15) * 64 + h * 32 + lq * 8];

    float bias_v[4];
    #pragma unroll
    for (int r = 0; r < 4; ++r) bias_v[r] = bias[o_base + lq * 4 + r];

    // ---- stage interior x=1..64: fixed (x,row) per thread, loop channels ----
    {
        const int sx  = 1 + (tid & 63);
        const int srr = tid >> 6;                       // 0..3
        const int gy  = y0 - 1 + srr;
        const int gx  = x0 + (tid & 63);                // always in [0,127]
        const bool yok = (unsigned)gy < HH;
        const float* ip = &image[((b * CIN) * HH + gy) * WW + gx];
        const int base = (srr * XW + sx) << 6;          // low 6 bits = 0
        const int swz  = (sx & 7) << 3;
        #pragma unroll 16
        for (int c2 = 0; c2 < 32; ++c2) {
            float v0 = 0.f, v1 = 0.f;
            if (yok) { v0 = ip[0]; v1 = ip[HW]; }
            ip += 2 * HW;
            __hip_bfloat162 pk = __float22bfloat162_rn(float2{v0, v1});
            *(__hip_bfloat162*)&s_img[base + ((2 * c2) ^ swz)] = pk;
        }
    }
    // ---- stage edge columns x=0,65: one element-pair per thread ----
    {
        const int e   = tid & 1;
        const int sx  = e ? (XW - 1) : 0;
        const int rr  = (tid >> 1) & 3;
        const int c2  = tid >> 3;                       // 0..31
        const int gy  = y0 - 1 + rr;
        const int gx  = x0 - 1 + sx;
        float v0 = 0.f, v1 = 0.f;
        if ((unsigned)gy < HH && (unsigned)gx < WW) {
            const float* p = &image[((b * CIN + 2 * c2) * HH + gy) * WW + gx];
            v0 = p[0]; v1 = p[HW];
        }
        __hip_bfloat162 pk = __float22bfloat162_rn(float2{v0, v1});
        *(__hip_bfloat162*)&s_img[img_idx(rr, sx, 2 * c2)] = pk;
    }
    // ---- stage depth rows ----
    for (int i = tid; i < 4 * XW; i += 256) {
        int rr = i / XW, x = i - rr * XW;
        int gy = y0 - 1 + rr, gx = x0 - 1 + x;
        float v = 0.f;
        if ((unsigned)gy < HH && (unsigned)gx < WW)
            v = depth[(b * HH + gy) * WW + gx];
        s_d[rr][x] = v;
    }
    __syncthreads();

    // ---- sim[yy][tap][p] = exp(-a*|d - d_tap0|), tap0 = (-1,-1) ----
    for (int i = tid; i < YPB * 9 * TPX; i += 256) {
        int p  = i & 63;
        int t  = i >> 6;                                // 0..17
        int yy = t / 9, tap = t - yy * 9;
        int ri = tap / 3, dj = tap - ri * 3;
        float dt = s_d[yy + ri][p + dj];
        float dc = s_d[yy][p];
        s_sim[yy][tap][p] = __expf(-ALPHA * fabsf(dt - dc));
    }
    __syncthreads();

    // ---- merged compute: LDS rows 1,2 feed BOTH y-rows (96 ds_reads, not 144) ----
    #pragma unroll
    for (int nt = 0; nt < 4; ++nt) {
        const int xb = nt * 16 + l15;
        f32x4 a0 = f32x4{0.f, 0.f, 0.f, 0.f};
        f32x4 a1 = f32x4{0.f, 0.f, 0.f, 0.f};

        #pragma unroll
        for (int r = 0; r < 4; ++r) {
            short8 bb[3][2];
            #pragma unroll
            for (int dj = 0; dj < 3; ++dj) {
                bb[dj][0] = *(const short8*)&s_img[img_idx(r, xb + dj, lq * 8)];
                bb[dj][1] = *(const short8*)&s_img[img_idx(r, xb + dj, 32 + lq * 8)];
            }
            if (r < 3) {                               // contributes to y0 (tapri=r)
                #pragma unroll
                for (int dj = 0; dj < 3; ++dj) {
                    const int tap = 3 * r + dj;
                    f32x4 tmp = __builtin_amdgcn_mfma_f32_16x16x32_bf16(
                        wfrag[tap][0], bb[dj][0], (f32x4){0.f, 0.f, 0.f, 0.f}, 0, 0, 0);
                    tmp = __builtin_amdgcn_mfma_f32_16x16x32_bf16(
                        wfrag[tap][1], bb[dj][1], tmp, 0, 0, 0);
                    const float sv = s_sim[0][tap][xb];
                    #pragma unroll
                    for (int e = 0; e < 4; ++e) a0[e] = fmaf(sv, tmp[e], a0[e]);
                }
            }
            if (r >= 1) {                              // contributes to y0+1 (tapri=r-1)
                #pragma unroll
                for (int dj = 0; dj < 3; ++dj) {
                    const int tap = 3 * (r - 1) + dj;
                    f32x4 tmp = __builtin_amdgcn_mfma_f32_16x16x32_bf16(
                        wfrag[tap][0], bb[dj][0], (f32x4){0.f, 0.f, 0.f, 0.f}, 0, 0, 0);
                    tmp = __builtin_amdgcn_mfma_f32_16x16x32_bf16(
                        wfrag[tap][1], bb[dj][1], tmp, 0, 0, 0);
                    const float sv = s_sim[1][tap][xb];
                    #pragma unroll
                    for (int e = 0; e < 4; ++e) a1[e] = fmaf(sv, tmp[e], a1[e]);
                }
            }
        }

        const int px = x0 + xb;
        #pragma unroll
        for (int rr = 0; rr < 4; ++rr) {
            const int o = o_base + lq * 4 + rr;
            out[((b * COUT + o) * HH + y0) * WW + px]     = a0[rr] + bias_v[rr];
            out[((b * COUT + o) * HH + y0 + 1) * WW + px] = a1[rr] + bias_v[rr];
        }
    }
}

extern "C" void kernel_launch(void* const* d_in, const int* in_sizes, int n_in,
                              void* d_out, int out_size, void* d_ws, size_t ws_size,
                              hipStream_t stream) {
    const float* image  = (const float*)d_in[0];
    const float* depth  = (const float*)d_in[1];
    const float* weight = (const float*)d_in[2];
    const float* bias   = (const float*)d_in[3];
    float* out = (float*)d_out;
    __hip_bfloat16* wt = (__hip_bfloat16*)d_ws;       // 9*64*64 bf16 = 73728 B

    transpose_w<<<(9 * 64 * 64 + 255) / 256, 256, 0, stream>>>(weight, wt);

    dim3 grid(BATCH * (HH / YPB) * (WW / TPX));        // 1024
    depthconv_fused<<<grid, 256, 0, stream>>>(image, depth, bias,
                                              (const short*)wt, out);
}